// Round 1
// baseline (337.959 us; speedup 1.0000x reference)
//
#include <hip/hip_runtime.h>
#include <hip/hip_bf16.h>

#define N_NODES 50000
#define N_EDGES 800000
#define D_IN    128
#define D_HID   256
#define D_OUT   64

typedef __bf16 bf16x8 __attribute__((ext_vector_type(8)));
typedef float  f32x4  __attribute__((ext_vector_type(4)));

__device__ __forceinline__ ushort f2bf(float f) {
    __hip_bfloat16 h = __float2bfloat16(f);
    return __builtin_bit_cast(ushort, h);
}

// ---------------- CSR build ----------------

__global__ void k_zero(int* __restrict__ p, int n) {
    int i = blockIdx.x * 256 + threadIdx.x;
    if (i < n) p[i] = 0;
}

__global__ void k_hist(const int* __restrict__ ei, int* __restrict__ cnt) {
    int e = blockIdx.x * 256 + threadIdx.x;
    if (e < N_EDGES) atomicAdd(&cnt[ei[N_EDGES + e]], 1);
}

__global__ __launch_bounds__(1024) void k_scan(const int* __restrict__ cnt,
                                               int* __restrict__ offs,
                                               int* __restrict__ cursor) {
    __shared__ int ws[1024];
    int tid = threadIdx.x;
    const int PER = 49;  // 49*1024 >= 50000
    int start = tid * PER;
    int stop  = start + PER; if (stop > N_NODES) stop = N_NODES;
    int sum = 0;
    for (int i = start; i < stop; ++i) sum += cnt[i];
    ws[tid] = sum;
    __syncthreads();
    // Hillis-Steele inclusive scan over 1024 thread-sums
    for (int off = 1; off < 1024; off <<= 1) {
        int v = (tid >= off) ? ws[tid - off] : 0;
        __syncthreads();
        ws[tid] += v;
        __syncthreads();
    }
    int run = ws[tid] - sum;  // exclusive prefix for this thread's range
    for (int i = start; i < stop; ++i) {
        int c = cnt[i];
        offs[i] = run; cursor[i] = run;
        run += c;
    }
    if (tid == 1023) offs[N_NODES] = ws[1023];
}

__global__ void k_scatter(const int* __restrict__ ei, int* __restrict__ cursor,
                          int* __restrict__ elist) {
    int e = blockIdx.x * 256 + threadIdx.x;
    if (e < N_EDGES) {
        int d = ei[N_EDGES + e];
        int pos = atomicAdd(&cursor[d], 1);
        elist[pos] = ei[e];
    }
}

// ---------------- weight prep: transpose + bf16 cast ----------------
// W [K,N] f32 row-major -> WT [N,K] bf16 row-major
__global__ void k_transpose(const float* __restrict__ W, ushort* __restrict__ WT,
                            int K, int N) {
    int t = blockIdx.x * 256 + threadIdx.x;
    if (t < K * N) {
        int k = t / N, n = t % N;
        WT[n * K + k] = f2bf(W[t]);
    }
}

// ---------------- aggregation: hsum[i] = x[i] + sum_{j in adj(i)} x[j] ----------------
// one 32-lane group per node, float4 per lane (32*16B = 512B row)
__global__ __launch_bounds__(256) void k_aggregate(const float* __restrict__ x,
                                                   const int* __restrict__ offs,
                                                   const int* __restrict__ elist,
                                                   ushort* __restrict__ hsum) {
    int g = threadIdx.x >> 5, lane = threadIdx.x & 31;
    int node = blockIdx.x * 8 + g;
    if (node >= N_NODES) return;
    const float4* x4 = (const float4*)x;
    float4 acc = x4[node * 32 + lane];
    int beg = offs[node], end = offs[node + 1];
    for (int base = beg; base < end; base += 32) {
        int m = end - base;
        int idx = 0;
        if (lane < m) idx = elist[base + lane];
        int c = m < 32 ? m : 32;
        for (int j = 0; j < c; ++j) {
            int s = __shfl(idx, j, 32);
            float4 v = x4[s * 32 + lane];
            acc.x += v.x; acc.y += v.y; acc.z += v.z; acc.w += v.w;
        }
    }
    ushort4 o;
    o.x = f2bf(acc.x); o.y = f2bf(acc.y); o.z = f2bf(acc.z); o.w = f2bf(acc.w);
    *(ushort4*)(hsum + node * 128 + lane * 4) = o;
}

// ---------------- bf16 MFMA GEMM: C[M,Nfull] = act(A[M,K] @ WT^T + bias) ----------------
// block: 64x64 output tile, 4 waves (each wave: 16 rows x 64 cols = 4 MFMA tiles)
template <int K, bool RELU, bool OUTF32>
__global__ __launch_bounds__(256) void k_gemm(const ushort* __restrict__ Ain,
                                              const ushort* __restrict__ WT,
                                              const float* __restrict__ bias,
                                              void* __restrict__ Cout,
                                              int M, int Nfull) {
    constexpr int KP = 136;  // +8 bf16 pad: 272B row stride -> 2-way bank alias (free)
    __shared__ ushort sA[64 * KP];
    __shared__ ushort sB[64 * KP];
    int m0 = blockIdx.x * 64, n0 = blockIdx.y * 64;
    int tid = threadIdx.x;
    int wid = tid >> 6, lane = tid & 63;

    f32x4 acc[4];
    acc[0] = 0; acc[1] = 0; acc[2] = 0; acc[3] = 0;

    for (int kb = 0; kb < K; kb += 128) {
        if (kb) __syncthreads();
        // stage A tile [64 x 128] and B tile [64 x 128] (bf16, 16B chunks)
        for (int c = tid; c < 64 * 16; c += 256) {
            int r = c >> 4, k8 = c & 15;
            uint4 v = make_uint4(0, 0, 0, 0);
            int gr = m0 + r;
            if (gr < M) v = *(const uint4*)(Ain + (size_t)gr * K + kb + k8 * 8);
            *(uint4*)(sA + r * KP + k8 * 8) = v;
            uint4 w = *(const uint4*)(WT + (size_t)(n0 + r) * K + kb + k8 * 8);
            *(uint4*)(sB + r * KP + k8 * 8) = w;
        }
        __syncthreads();

        int arow = (wid << 4) + (lane & 15);
        int kq = (lane >> 4) << 3;
#pragma unroll
        for (int kk = 0; kk < 128; kk += 32) {
            uint4 ta = *(const uint4*)(sA + arow * KP + kk + kq);
            bf16x8 a = __builtin_bit_cast(bf16x8, ta);
#pragma unroll
            for (int n = 0; n < 4; ++n) {
                uint4 tb = *(const uint4*)(sB + (n * 16 + (lane & 15)) * KP + kk + kq);
                bf16x8 b = __builtin_bit_cast(bf16x8, tb);
                acc[n] = __builtin_amdgcn_mfma_f32_16x16x32_bf16(a, b, acc[n], 0, 0, 0);
            }
        }
    }

    // epilogue: C[row=(lane>>4)*4+r][col=lane&15] per tile (m89-verified layout)
    int r0 = m0 + (wid << 4) + ((lane >> 4) << 2);
    int cb = n0 + (lane & 15);
#pragma unroll
    for (int n = 0; n < 4; ++n) {
        int col = cb + n * 16;
        float bv = bias[col];
#pragma unroll
        for (int r = 0; r < 4; ++r) {
            int grow = r0 + r;
            if (grow < M) {
                float v = acc[n][r] + bv;
                if (RELU) v = fmaxf(v, 0.0f);
                if (OUTF32) ((float*)Cout)[(size_t)grow * Nfull + col] = v;
                else        ((ushort*)Cout)[(size_t)grow * Nfull + col] = f2bf(v);
            }
        }
    }
}

// ---------------- launch ----------------

extern "C" void kernel_launch(void* const* d_in, const int* in_sizes, int n_in,
                              void* d_out, int out_size, void* d_ws, size_t ws_size,
                              hipStream_t stream) {
    const float* x  = (const float*)d_in[0];
    const int*   ei = (const int*)d_in[1];   // [2, 800000]: row0 = src, row1 = dst
    const float* W1 = (const float*)d_in[2];
    const float* b1 = (const float*)d_in[3];
    const float* W2 = (const float*)d_in[4];
    const float* b2 = (const float*)d_in[5];
    const float* Wc = (const float*)d_in[6];
    const float* bc = (const float*)d_in[7];
    float* out = (float*)d_out;

    // workspace carve (all segments 16B-aligned)
    char* p = (char*)d_ws;
    int* offs   = (int*)p; p += (N_NODES + 4) * 4;      // 50004 ints
    int* cursor = (int*)p; p += N_NODES * 4;
    int* cnt    = (int*)p; p += N_NODES * 4;
    int* elist  = (int*)p; p += N_EDGES * 4;
    ushort* W1T = (ushort*)p; p += 256 * 128 * 2;
    ushort* W2T = (ushort*)p; p += 256 * 256 * 2;
    ushort* WcT = (ushort*)p; p += 64 * 256 * 2;
    ushort* hsum = (ushort*)p; p += (size_t)N_NODES * 128 * 2;
    ushort* Abuf = (ushort*)p; p += (size_t)N_NODES * 256 * 2;
    ushort* Bbuf = (ushort*)p; p += (size_t)N_NODES * 256 * 2;

    k_zero<<<(N_NODES + 255) / 256, 256, 0, stream>>>(cnt, N_NODES);
    k_hist<<<N_EDGES / 256, 256, 0, stream>>>(ei, cnt);
    k_scan<<<1, 1024, 0, stream>>>(cnt, offs, cursor);
    k_scatter<<<N_EDGES / 256, 256, 0, stream>>>(ei, cursor, elist);

    k_transpose<<<(128 * 256 + 255) / 256, 256, 0, stream>>>(W1, W1T, 128, 256);
    k_transpose<<<(256 * 256 + 255) / 256, 256, 0, stream>>>(W2, W2T, 256, 256);
    k_transpose<<<(256 * 64 + 255) / 256, 256, 0, stream>>>(Wc, WcT, 256, 64);

    k_aggregate<<<N_NODES / 8, 256, 0, stream>>>(x, offs, elist, hsum);

    dim3 g1((N_NODES + 63) / 64, 256 / 64);
    k_gemm<128, true, false><<<g1, 256, 0, stream>>>(hsum, W1T, b1, Abuf, N_NODES, D_HID);
    dim3 g2((N_NODES + 63) / 64, 256 / 64);
    k_gemm<256, true, false><<<g2, 256, 0, stream>>>(Abuf, W2T, b2, Bbuf, N_NODES, D_HID);
    dim3 g3((N_NODES + 63) / 64, 64 / 64);
    k_gemm<256, false, true><<<g3, 256, 0, stream>>>(Bbuf, WcT, bc, out, N_NODES, D_OUT);
}

// Round 2
// 234.132 us; speedup vs baseline: 1.4435x; 1.4435x over previous
//
#include <hip/hip_runtime.h>
#include <hip/hip_bf16.h>

#define N_NODES 50000
#define N_EDGES 800000
#define D_IN    128
#define D_HID   256
#define D_OUT   64
#define NB_SCAN 196  // ceil(50000/256)

typedef __bf16 bf16x8 __attribute__((ext_vector_type(8)));
typedef float  f32x4  __attribute__((ext_vector_type(4)));

__device__ __forceinline__ ushort f2bf(float f) {
    __hip_bfloat16 h = __float2bfloat16(f);
    return __builtin_bit_cast(ushort, h);
}

// ---------------- CSR build ----------------

__global__ void k_hist(const int* __restrict__ ei, int* __restrict__ cnt) {
    int e = blockIdx.x * 256 + threadIdx.x;
    if (e < N_EDGES) atomicAdd(&cnt[ei[N_EDGES + e]], 1);
}

// phase 1: per-block exclusive scan of 256 counts -> tmp; block totals -> bsum
__global__ __launch_bounds__(256) void k_scan1(const int* __restrict__ cnt,
                                               int* __restrict__ tmp,
                                               int* __restrict__ bsum) {
    __shared__ int ws[256];
    int t = threadIdx.x, i = blockIdx.x * 256 + t;
    int v = (i < N_NODES) ? cnt[i] : 0;
    ws[t] = v;
    __syncthreads();
#pragma unroll
    for (int off = 1; off < 256; off <<= 1) {
        int u = (t >= off) ? ws[t - off] : 0;
        __syncthreads();
        ws[t] += u;
        __syncthreads();
    }
    if (i < N_NODES) tmp[i] = ws[t] - v;
    if (t == 255) bsum[blockIdx.x] = ws[255];
}

// phase 2: single block scans the 196 block sums -> boff (exclusive); total -> offs[N]
__global__ __launch_bounds__(256) void k_scan2(const int* __restrict__ bsum,
                                               int* __restrict__ boff,
                                               int* __restrict__ offs) {
    __shared__ int ws[256];
    int t = threadIdx.x;
    int v = (t < NB_SCAN) ? bsum[t] : 0;
    ws[t] = v;
    __syncthreads();
#pragma unroll
    for (int off = 1; off < 256; off <<= 1) {
        int u = (t >= off) ? ws[t - off] : 0;
        __syncthreads();
        ws[t] += u;
        __syncthreads();
    }
    if (t < NB_SCAN) boff[t] = ws[t] - v;
    if (t == 255) offs[N_NODES] = ws[255];
}

// phase 3: offs[i] = cursor[i] = tmp[i] + boff[block]
__global__ __launch_bounds__(256) void k_scan3(const int* __restrict__ tmp,
                                               const int* __restrict__ boff,
                                               int* __restrict__ offs,
                                               int* __restrict__ cursor) {
    int i = blockIdx.x * 256 + threadIdx.x;
    if (i < N_NODES) {
        int o = tmp[i] + boff[blockIdx.x];
        offs[i] = o;
        cursor[i] = o;
    }
}

__global__ void k_scatter(const int* __restrict__ ei, int* __restrict__ cursor,
                          int* __restrict__ elist) {
    int e = blockIdx.x * 256 + threadIdx.x;
    if (e < N_EDGES) {
        int d = ei[N_EDGES + e];
        int pos = atomicAdd(&cursor[d], 1);
        elist[pos] = ei[e];
    }
}

// ---------------- weight prep: all three transposes in one kernel ----------------
// W [K,N] f32 row-major -> WT [N,K] bf16 row-major
__device__ __forceinline__ void transpose_one(const float* W, ushort* WT,
                                              int K, int N, int t) {
    int k = t / N, n = t % N;
    WT[n * K + k] = f2bf(W[t]);
}

__global__ void k_transpose_all(const float* __restrict__ W1, ushort* __restrict__ W1T,
                                const float* __restrict__ W2, ushort* __restrict__ W2T,
                                const float* __restrict__ Wc, ushort* __restrict__ WcT) {
    int t = blockIdx.x * 256 + threadIdx.x;
    const int S1 = 128 * 256, S2 = 256 * 256, S3 = 256 * 64;
    if (t < S1) transpose_one(W1, W1T, 128, 256, t);
    else if (t < S1 + S2) transpose_one(W2, W2T, 256, 256, t - S1);
    else if (t < S1 + S2 + S3) transpose_one(Wc, WcT, 256, 64, t - S1 - S2);
}

// ---------------- aggregation: hsum[i] = x[i] + sum_{j in adj(i)} x[j] ----------------
__global__ __launch_bounds__(256) void k_aggregate(const float* __restrict__ x,
                                                   const int* __restrict__ offs,
                                                   const int* __restrict__ elist,
                                                   ushort* __restrict__ hsum) {
    int g = threadIdx.x >> 5, lane = threadIdx.x & 31;
    int node = blockIdx.x * 8 + g;
    if (node >= N_NODES) return;
    const float4* x4 = (const float4*)x;
    float4 acc = x4[node * 32 + lane];
    int beg = offs[node], end = offs[node + 1];
    for (int base = beg; base < end; base += 32) {
        int m = end - base;
        int idx = 0;
        if (lane < m) idx = elist[base + lane];
        int c = m < 32 ? m : 32;
        for (int j = 0; j < c; ++j) {
            int s = __shfl(idx, j, 32);
            float4 v = x4[s * 32 + lane];
            acc.x += v.x; acc.y += v.y; acc.z += v.z; acc.w += v.w;
        }
    }
    ushort4 o;
    o.x = f2bf(acc.x); o.y = f2bf(acc.y); o.z = f2bf(acc.z); o.w = f2bf(acc.w);
    *(ushort4*)(hsum + node * 128 + lane * 4) = o;
}

// ---------------- bf16 MFMA GEMM: C[M,Nfull] = act(A[M,K] @ WT^T + bias) ----------------
template <int K, bool RELU, bool OUTF32>
__global__ __launch_bounds__(256) void k_gemm(const ushort* __restrict__ Ain,
                                              const ushort* __restrict__ WT,
                                              const float* __restrict__ bias,
                                              void* __restrict__ Cout,
                                              int M, int Nfull) {
    constexpr int KP = 136;  // +8 bf16 pad: 272B row stride -> 2-way bank alias (free)
    __shared__ ushort sA[64 * KP];
    __shared__ ushort sB[64 * KP];
    int m0 = blockIdx.x * 64, n0 = blockIdx.y * 64;
    int tid = threadIdx.x;
    int wid = tid >> 6, lane = tid & 63;

    f32x4 acc[4];
    acc[0] = 0; acc[1] = 0; acc[2] = 0; acc[3] = 0;

    for (int kb = 0; kb < K; kb += 128) {
        if (kb) __syncthreads();
        for (int c = tid; c < 64 * 16; c += 256) {
            int r = c >> 4, k8 = c & 15;
            uint4 v = make_uint4(0, 0, 0, 0);
            int gr = m0 + r;
            if (gr < M) v = *(const uint4*)(Ain + (size_t)gr * K + kb + k8 * 8);
            *(uint4*)(sA + r * KP + k8 * 8) = v;
            uint4 w = *(const uint4*)(WT + (size_t)(n0 + r) * K + kb + k8 * 8);
            *(uint4*)(sB + r * KP + k8 * 8) = w;
        }
        __syncthreads();

        int arow = (wid << 4) + (lane & 15);
        int kq = (lane >> 4) << 3;
#pragma unroll
        for (int kk = 0; kk < 128; kk += 32) {
            uint4 ta = *(const uint4*)(sA + arow * KP + kk + kq);
            bf16x8 a = __builtin_bit_cast(bf16x8, ta);
#pragma unroll
            for (int n = 0; n < 4; ++n) {
                uint4 tb = *(const uint4*)(sB + (n * 16 + (lane & 15)) * KP + kk + kq);
                bf16x8 b = __builtin_bit_cast(bf16x8, tb);
                acc[n] = __builtin_amdgcn_mfma_f32_16x16x32_bf16(a, b, acc[n], 0, 0, 0);
            }
        }
    }

    int r0 = m0 + (wid << 4) + ((lane >> 4) << 2);
    int cb = n0 + (lane & 15);
#pragma unroll
    for (int n = 0; n < 4; ++n) {
        int col = cb + n * 16;
        float bv = bias[col];
#pragma unroll
        for (int r = 0; r < 4; ++r) {
            int grow = r0 + r;
            if (grow < M) {
                float v = acc[n][r] + bv;
                if (RELU) v = fmaxf(v, 0.0f);
                if (OUTF32) ((float*)Cout)[(size_t)grow * Nfull + col] = v;
                else        ((ushort*)Cout)[(size_t)grow * Nfull + col] = f2bf(v);
            }
        }
    }
}

// ---------------- launch ----------------

extern "C" void kernel_launch(void* const* d_in, const int* in_sizes, int n_in,
                              void* d_out, int out_size, void* d_ws, size_t ws_size,
                              hipStream_t stream) {
    const float* x  = (const float*)d_in[0];
    const int*   ei = (const int*)d_in[1];   // [2, 800000]: row0 = src, row1 = dst
    const float* W1 = (const float*)d_in[2];
    const float* b1 = (const float*)d_in[3];
    const float* W2 = (const float*)d_in[4];
    const float* b2 = (const float*)d_in[5];
    const float* Wc = (const float*)d_in[6];
    const float* bc = (const float*)d_in[7];
    float* out = (float*)d_out;

    // workspace carve (all segments 16B-aligned)
    char* p = (char*)d_ws;
    int* offs   = (int*)p; p += (N_NODES + 4) * 4;
    int* cursor = (int*)p; p += N_NODES * 4;
    int* cnt    = (int*)p; p += N_NODES * 4;
    int* tmp    = (int*)p; p += N_NODES * 4;
    int* bsum   = (int*)p; p += 256 * 4;
    int* boff   = (int*)p; p += 256 * 4;
    int* elist  = (int*)p; p += N_EDGES * 4;
    ushort* W1T = (ushort*)p; p += 256 * 128 * 2;
    ushort* W2T = (ushort*)p; p += 256 * 256 * 2;
    ushort* WcT = (ushort*)p; p += 64 * 256 * 2;
    ushort* hsum = (ushort*)p; p += (size_t)N_NODES * 128 * 2;
    ushort* Abuf = (ushort*)p; p += (size_t)N_NODES * 256 * 2;
    ushort* Bbuf = (ushort*)p; p += (size_t)N_NODES * 256 * 2;

    hipMemsetAsync(cnt, 0, N_NODES * 4, stream);
    k_hist<<<N_EDGES / 256, 256, 0, stream>>>(ei, cnt);
    k_scan1<<<NB_SCAN, 256, 0, stream>>>(cnt, tmp, bsum);
    k_scan2<<<1, 256, 0, stream>>>(bsum, boff, offs);
    k_scan3<<<NB_SCAN, 256, 0, stream>>>(tmp, boff, offs, cursor);
    k_scatter<<<N_EDGES / 256, 256, 0, stream>>>(ei, cursor, elist);

    k_transpose_all<<<(128 * 256 + 256 * 256 + 256 * 64 + 255) / 256, 256, 0, stream>>>(
        W1, W1T, W2, W2T, Wc, WcT);

    k_aggregate<<<N_NODES / 8, 256, 0, stream>>>(x, offs, elist, hsum);

    dim3 g1((N_NODES + 63) / 64, 256 / 64);
    k_gemm<128, true, false><<<g1, 256, 0, stream>>>(hsum, W1T, b1, Abuf, N_NODES, D_HID);
    dim3 g2((N_NODES + 63) / 64, 256 / 64);
    k_gemm<256, true, false><<<g2, 256, 0, stream>>>(Abuf, W2T, b2, Bbuf, N_NODES, D_HID);
    dim3 g3((N_NODES + 63) / 64, 64 / 64);
    k_gemm<256, false, true><<<g3, 256, 0, stream>>>(Bbuf, WcT, bc, out, N_NODES, D_OUT);
}